// Round 1
// 330.962 us; speedup vs baseline: 1.0323x; 1.0323x over previous
//
#include <hip/hip_runtime.h>
#include <math.h>

#define NN 50000
#define EE 640000
#define IND 23
#define HID 128
#define MIDD 64
#define NCLS 12
#define NB 49          // ceil(NN / 1024) scan chunks
#define QS 32766.0f
#define INVQS (1.0f / 32766.0f)

typedef short short8v __attribute__((ext_vector_type(8)));

// ---- graph build ----------------------------------------------------------

__global__ void k_count(const int* __restrict__ dst, int* __restrict__ cnt, int e) {
    int i = blockIdx.x * blockDim.x + threadIdx.x;
    if (i < e) atomicAdd(&cnt[dst[i]], 1);
}

__global__ __launch_bounds__(256) void k_scan_local(const int* __restrict__ cnt,
                                                    int* __restrict__ row_ptr,
                                                    float* __restrict__ dinv,
                                                    int* __restrict__ sums) {
    __shared__ int wtot[4];
    const int tid = threadIdx.x;
    const int wid = tid >> 6, lane = tid & 63;
    const int base = blockIdx.x * 1024 + tid * 4;
    int v[4];
#pragma unroll
    for (int t = 0; t < 4; ++t) {
        int i = base + t;
        v[t] = (i < NN) ? cnt[i] : 0;
        if (i < NN) dinv[i] = rsqrtf((float)v[t] + 1.0f);  // +1 self loop
    }
    int slocal = v[0] + v[1] + v[2] + v[3];
    int val = slocal;
#pragma unroll
    for (int off = 1; off < 64; off <<= 1) {
        int t = __shfl_up(val, off, 64);
        if (lane >= off) val += t;
    }
    if (lane == 63) wtot[wid] = val;
    __syncthreads();
    int woff = 0;
#pragma unroll
    for (int w = 0; w < 4; ++w) woff += (w < wid) ? wtot[w] : 0;
    int run = woff + val - slocal;
#pragma unroll
    for (int t = 0; t < 4; ++t) {
        int i = base + t;
        if (i < NN) row_ptr[i] = run;
        run += v[t];
    }
    if (tid == 255) sums[blockIdx.x] = woff + val;
}

__global__ void k_scan_sums(const int* __restrict__ sums, int* __restrict__ offs,
                            int* __restrict__ row_ptr) {
    const int lane = threadIdx.x;
    int v = (lane < NB) ? sums[lane] : 0;
    int val = v;
#pragma unroll
    for (int off = 1; off < 64; off <<= 1) {
        int t = __shfl_up(val, off, 64);
        if (lane >= off) val += t;
    }
    if (lane < NB) offs[lane] = val - v;
    if (lane == NB - 1) row_ptr[NN] = val;
}

// lean 49-block scan finalize ONLY (pad lives in its own wide launch —
// merging it here collapsed to 2% occupancy and cost ~50 µs, round 11)
__global__ __launch_bounds__(256) void k_scan_apply(int* __restrict__ row_ptr,
                                                    const int* __restrict__ offs,
                                                    int* __restrict__ cursor) {
    const int base = blockIdx.x * 1024 + threadIdx.x * 4;
    const int o = offs[blockIdx.x];
#pragma unroll
    for (int t = 0; t < 4; ++t) {
        int i = base + t;
        if (i < NN) {
            int rp = row_ptr[i] + o;
            row_ptr[i] = rp;
            cursor[i] = rp;
        }
    }
}

// fill CSR with packed {src, dinv[src]} — moves the per-edge dinv gather out
// of the two k_aggq passes (one gather pass instead of two, and the agg
// latency chain loses a dependent random load)
__global__ void k_fill(const int* __restrict__ src, const int* __restrict__ dst,
                       int* __restrict__ cursor, const float* __restrict__ dinv,
                       int2* __restrict__ e_sn, int e) {
    int i = blockIdx.x * blockDim.x + threadIdx.x;
    if (i < e) {
        int s = src[i];
        int d = dst[i];
        float w = dinv[s];
        int pos = atomicAdd(&cursor[d], 1);
        e_sn[pos] = make_int2(s, __float_as_int(w));
    }
}

// pad x rows 23 -> 32 floats, pre-scaled by dinv[node] (wide 6250-block grid)
__global__ __launch_bounds__(256) void k_pad(const float* __restrict__ x,
                                             const float* __restrict__ dinv,
                                             float* __restrict__ xp) {
    int i = blockIdx.x * 256 + threadIdx.x;   // over NN*32
    int node = i >> 5, f = i & 31;
    xp[i] = (f < IND) ? x[node * IND + f] * dinv[node] : 0.f;
}

// collapse the linear head: Wcc = Wc1 @ Wc2 (128x12), bcc = bc1 @ Wc2 + bc2.
// Valid because there is NO nonlinearity between the two head matmuls
// (dropout is identity in eval). 1536 outputs, ~2 µs.
__global__ void k_wcc(const float* __restrict__ Wc1, const float* __restrict__ bc1,
                      const float* __restrict__ Wc2, const float* __restrict__ bc2,
                      float* __restrict__ Wcc, float* __restrict__ bcc) {
    int t = blockIdx.x * 256 + threadIdx.x;
    if (t < HID * NCLS) {
        int k = t / NCLS, c = t % NCLS;
        float s = 0.f;
#pragma unroll 8
        for (int j = 0; j < MIDD; ++j) s += Wc1[k * MIDD + j] * Wc2[j * NCLS + c];
        Wcc[t] = s;
    }
    if (t < NCLS) {
        float s = bc2[t];
#pragma unroll 8
        for (int j = 0; j < MIDD; ++j) s += bc1[j] * Wc2[j * NCLS + t];
        bcc[t] = s;
    }
}

// ---- layer 1 fused: q1 = quant( tanh( (A @ x) @ W1 + b1 ) ) ---------------
// wave per node; 8 edges in flight. Remainder shfl runs wave-uniform
// (ds_bpermute from an EXEC-masked source lane is undefined — round-6/7 bug).
__global__ __launch_bounds__(256) void k_l1(const float* __restrict__ xp,
                                            const float* __restrict__ W1,
                                            const float* __restrict__ b1,
                                            const int* __restrict__ row_ptr,
                                            const int2* __restrict__ e_sn,
                                            const float* __restrict__ dinv,
                                            short* __restrict__ outq) {
    const int tid = threadIdx.x;
    const int i = blockIdx.x * 4 + (tid >> 6);
    const int lane = tid & 63;
    const int slot = lane >> 3;     // 8 edge slots
    const int f = lane & 7;         // float4 index within 32-float row
    const float4* xp4 = (const float4*)xp;
    const int beg = row_ptr[i];
    const int deg = row_ptr[i + 1] - beg;
    float4 acc = make_float4(0.f, 0.f, 0.f, 0.f);
    for (int base = 0; base < deg; base += 64) {
        const int cnt = min(64, deg - base);
        int s_l = 0;
        if (lane < cnt) s_l = e_sn[beg + base + lane].x;
        int e = 0;
        for (; e + 8 <= cnt; e += 8) {
            int s = __shfl(s_l, e + slot, 64);
            float4 v = xp4[s * 8 + f];
            acc.x += v.x; acc.y += v.y; acc.z += v.z; acc.w += v.w;
        }
        if (e < cnt) {                          // wave-uniform shfl
            int s = __shfl(s_l, e + slot, 64);
            if (e + slot < cnt) {
                float4 v = xp4[s * 8 + f];
                acc.x += v.x; acc.y += v.y; acc.z += v.z; acc.w += v.w;
            }
        }
    }
#pragma unroll
    for (int off = 32; off >= 8; off >>= 1) {
        acc.x += __shfl_down(acc.x, off, 64);
        acc.y += __shfl_down(acc.y, off, 64);
        acc.z += __shfl_down(acc.z, off, 64);
        acc.w += __shfl_down(acc.w, off, 64);
    }
    const float di = dinv[i];
    if (lane < 8) {
        float4 v = xp4[i * 8 + lane];   // self row (pre-folded)
        acc.x = (acc.x + v.x) * di; acc.y = (acc.y + v.y) * di;
        acc.z = (acc.z + v.z) * di; acc.w = (acc.w + v.w) * di;
    }
    float a0 = b1[lane], a1 = b1[lane + 64];
#pragma unroll
    for (int k = 0; k < IND; ++k) {
        float comp = ((k & 3) == 0) ? acc.x : ((k & 3) == 1) ? acc.y
                   : ((k & 3) == 2) ? acc.z : acc.w;
        float xk = __shfl(comp, k >> 2, 64);
        a0 += xk * W1[k * HID + lane];
        a1 += xk * W1[k * HID + lane + 64];
    }
    outq[i * HID + lane]      = (short)__float2int_rn(tanhf(a0) * QS);
    outq[i * HID + lane + 64] = (short)__float2int_rn(tanhf(a1) * QS);
}

// ---- aggregation over int16 tanh rows (lean: low VGPR, 0 LDS, high occ) ---
// aggf_i = dinv_i * ( sum_s dinv_s*q_s + dinv_i*q_i ) / QS
// dinv_s arrives packed with the edge (e_sn.y) — coalesced, no gather.
__global__ __launch_bounds__(256) void k_aggq(const short* __restrict__ hq,
                                              const int* __restrict__ row_ptr,
                                              const int2* __restrict__ e_sn,
                                              const float* __restrict__ dinv,
                                              float* __restrict__ aggf) {
    const int tid = threadIdx.x;
    const int i = blockIdx.x * 4 + (tid >> 6);
    const int lane = tid & 63;
    const int slot = lane >> 4;     // 4 edge slots
    const int f = lane & 15;        // short8 index within 128-short row
    const short8v* h8 = (const short8v*)hq;
    const int beg = row_ptr[i];
    const int deg = row_ptr[i + 1] - beg;
    float facc[8];
#pragma unroll
    for (int t = 0; t < 8; ++t) facc[t] = 0.f;
    for (int base = 0; base < deg; base += 64) {
        const int cnt = min(64, deg - base);
        int s_l = 0; float n_l = 0.f;
        if (lane < cnt) {
            int2 sn = e_sn[beg + base + lane];
            s_l = sn.x;
            n_l = __int_as_float(sn.y);
        }
        int e = 0;
#pragma unroll 4
        for (; e + 4 <= cnt; e += 4) {
            int s = __shfl(s_l, e + slot, 64);
            float nr = __shfl(n_l, e + slot, 64);
            short8v v = h8[s * 16 + f];
#pragma unroll
            for (int t = 0; t < 8; ++t) facc[t] += (float)v[t] * nr;
        }
        if (e < cnt) {                          // wave-uniform shfl
            int s = __shfl(s_l, e + slot, 64);
            float nr = __shfl(n_l, e + slot, 64);
            if (e + slot < cnt) {
                short8v v = h8[s * 16 + f];
#pragma unroll
                for (int t = 0; t < 8; ++t) facc[t] += (float)v[t] * nr;
            }
        }
    }
#pragma unroll
    for (int off = 32; off >= 16; off >>= 1)
#pragma unroll
        for (int t = 0; t < 8; ++t) facc[t] += __shfl_down(facc[t], off, 64);
    if (lane < 16) {
        const float di = dinv[i];
        const float sc = di * INVQS;
        short8v v = h8[i * 16 + lane];          // self row
        float4 o0, o1;
        o0.x = (facc[0] + di * (float)v[0]) * sc;
        o0.y = (facc[1] + di * (float)v[1]) * sc;
        o0.z = (facc[2] + di * (float)v[2]) * sc;
        o0.w = (facc[3] + di * (float)v[3]) * sc;
        o1.x = (facc[4] + di * (float)v[4]) * sc;
        o1.y = (facc[5] + di * (float)v[5]) * sc;
        o1.z = (facc[6] + di * (float)v[6]) * sc;
        o1.w = (facc[7] + di * (float)v[7]) * sc;
        ((float4*)aggf)[i * 32 + lane * 2]     = o0;
        ((float4*)aggf)[i * 32 + lane * 2 + 1] = o1;
    }
}

// ---- tiled 128x128 GEMM with tanh epilogue (25.6 KB LDS — keep it lean) ---
// out = tanh(hin @ W + b).
//   qout != 0 : int16-quantized store (layers 1->2, 2->3 handoff)
//   outp != 0 : fused classifier head out = h3 @ Wcc + bcc (layer 3; h3 never
//               touches global memory — tile goes through LDS in two halves,
//               reusing the Hs/Ws region)
// Inner loop reads Hs as float4 over kk: 12 LDS instrs per 4k instead of 24
// (old scalar-Hs version was LDS-issue-bound).
__global__ __launch_bounds__(256) void k_gemmT(const float* __restrict__ hin,
                                               const float* __restrict__ W,
                                               const float* __restrict__ bias,
                                               short* __restrict__ qout,
                                               const float* __restrict__ Wcc,
                                               const float* __restrict__ bcc,
                                               float* __restrict__ outp) {
    __shared__ float Smem[64 * 36 + 32 * 128];   // 6400 floats = 25.6 KB
    float* Hs = Smem;                 // 64 x 36
    float* Ws = Smem + 64 * 36;       // 32 x 128
    const int tid = threadIdx.x;
    const int b0 = blockIdx.x * 64;
    const int ng = tid >> 4;
    const int cg = tid & 15;
    const float4* hin4 = (const float4*)hin;
    const float4* W4 = (const float4*)W;

    float acc[4][8];
#pragma unroll
    for (int m = 0; m < 4; ++m)
#pragma unroll
        for (int c = 0; c < 8; ++c) acc[m][c] = 0.f;

    for (int ks = 0; ks < HID; ks += 32) {
#pragma unroll
        for (int t = 0; t < 2; ++t) {
            int id = t * 256 + tid;
            int row = id >> 3;
            int k4 = id & 7;
            int node = b0 + row;
            float4 v = make_float4(0.f, 0.f, 0.f, 0.f);
            if (node < NN) v = hin4[node * 32 + (ks >> 2) + k4];
            *(float4*)&Hs[row * 36 + k4 * 4] = v;
        }
#pragma unroll
        for (int t = 0; t < 4; ++t) {
            int id = t * 256 + tid;
            int row = id >> 5;
            int c4 = id & 31;
            *(float4*)&Ws[row * 128 + c4 * 4] = W4[(ks + row) * 32 + c4];
        }
        __syncthreads();
#pragma unroll
        for (int kk = 0; kk < 32; kk += 4) {
            float4 h4[4];
#pragma unroll
            for (int m = 0; m < 4; ++m)
                h4[m] = *(float4*)&Hs[(ng * 4 + m) * 36 + kk];
#pragma unroll
            for (int j = 0; j < 4; ++j) {
                float4 w0 = *(float4*)&Ws[(kk + j) * 128 + cg * 8];
                float4 w1 = *(float4*)&Ws[(kk + j) * 128 + cg * 8 + 4];
#pragma unroll
                for (int m = 0; m < 4; ++m) {
                    float hv = (j == 0) ? h4[m].x : (j == 1) ? h4[m].y
                             : (j == 2) ? h4[m].z : h4[m].w;
                    acc[m][0] += hv * w0.x; acc[m][1] += hv * w0.y;
                    acc[m][2] += hv * w0.z; acc[m][3] += hv * w0.w;
                    acc[m][4] += hv * w1.x; acc[m][5] += hv * w1.y;
                    acc[m][6] += hv * w1.z; acc[m][7] += hv * w1.w;
                }
            }
        }
        __syncthreads();
    }
    const float4* b4 = (const float4*)bias;
    float4 bb0 = b4[cg * 2], bb1 = b4[cg * 2 + 1];
#pragma unroll
    for (int m = 0; m < 4; ++m) {
        acc[m][0] = tanhf(acc[m][0] + bb0.x);
        acc[m][1] = tanhf(acc[m][1] + bb0.y);
        acc[m][2] = tanhf(acc[m][2] + bb0.z);
        acc[m][3] = tanhf(acc[m][3] + bb0.w);
        acc[m][4] = tanhf(acc[m][4] + bb1.x);
        acc[m][5] = tanhf(acc[m][5] + bb1.y);
        acc[m][6] = tanhf(acc[m][6] + bb1.z);
        acc[m][7] = tanhf(acc[m][7] + bb1.w);
    }

    if (outp == nullptr) {
#pragma unroll
        for (int m = 0; m < 4; ++m) {
            int node = b0 + ng * 4 + m;
            if (node < NN && qout) {
                short8v qv;
                qv[0] = (short)__float2int_rn(acc[m][0] * QS);
                qv[1] = (short)__float2int_rn(acc[m][1] * QS);
                qv[2] = (short)__float2int_rn(acc[m][2] * QS);
                qv[3] = (short)__float2int_rn(acc[m][3] * QS);
                qv[4] = (short)__float2int_rn(acc[m][4] * QS);
                qv[5] = (short)__float2int_rn(acc[m][5] * QS);
                qv[6] = (short)__float2int_rn(acc[m][6] * QS);
                qv[7] = (short)__float2int_rn(acc[m][7] * QS);
                ((short8v*)qout)[node * 16 + cg] = qv;
            }
        }
        return;
    }

    // ---- fused head: out = h3 @ Wcc + bcc, two 32-node halves through LDS --
    float* H3 = Smem;                  // 32 x 132 = 4224 floats
    float* WccS = Smem + 32 * 132;     // 128 x 12 = 1536 floats
    float* bccS = WccS + HID * NCLS;   // 12 floats  (total 5772 <= 6400)
    for (int t = tid; t < HID * NCLS; t += 256) WccS[t] = Wcc[t];
    if (tid < NCLS) bccS[tid] = bcc[tid];
#pragma unroll
    for (int h = 0; h < 2; ++h) {
        if (h) __syncthreads();        // previous half fully consumed
        if ((ng >> 3) == h) {          // this thread's 4 nodes are in half h
            int r = (ng - h * 8) * 4;
#pragma unroll
            for (int m = 0; m < 4; ++m) {
                *(float4*)&H3[(r + m) * 132 + cg * 8] =
                    make_float4(acc[m][0], acc[m][1], acc[m][2], acc[m][3]);
                *(float4*)&H3[(r + m) * 132 + cg * 8 + 4] =
                    make_float4(acc[m][4], acc[m][5], acc[m][6], acc[m][7]);
            }
        }
        __syncthreads();
        const int n32 = tid >> 3, oct = tid & 7;   // 32 nodes x 8 k-slices
        float a0 = 0.f, a1 = 0.f, a2 = 0.f, a3 = 0.f, a4 = 0.f, a5 = 0.f,
              a6 = 0.f, a7 = 0.f, a8 = 0.f, a9 = 0.f, a10 = 0.f, a11 = 0.f;
#pragma unroll
        for (int kk = 0; kk < 16; ++kk) {
            int k = kk * 8 + oct;      // oct-interleaved: Wcc banks conflict-free
            float hv = H3[n32 * 132 + k];
            const float4* wr = (const float4*)&WccS[k * NCLS];
            float4 wa = wr[0], wb = wr[1], wc = wr[2];
            a0 += hv * wa.x; a1 += hv * wa.y; a2  += hv * wa.z; a3  += hv * wa.w;
            a4 += hv * wb.x; a5 += hv * wb.y; a6  += hv * wb.z; a7  += hv * wb.w;
            a8 += hv * wc.x; a9 += hv * wc.y; a10 += hv * wc.z; a11 += hv * wc.w;
        }
#pragma unroll
        for (int off = 4; off; off >>= 1) {
            a0 += __shfl_down(a0, off, 64);   a1 += __shfl_down(a1, off, 64);
            a2 += __shfl_down(a2, off, 64);   a3 += __shfl_down(a3, off, 64);
            a4 += __shfl_down(a4, off, 64);   a5 += __shfl_down(a5, off, 64);
            a6 += __shfl_down(a6, off, 64);   a7 += __shfl_down(a7, off, 64);
            a8 += __shfl_down(a8, off, 64);   a9 += __shfl_down(a9, off, 64);
            a10 += __shfl_down(a10, off, 64); a11 += __shfl_down(a11, off, 64);
        }
        int node = b0 + h * 32 + n32;
        if (oct == 0 && node < NN) {
            float4* op = (float4*)&outp[node * NCLS];
            op[0] = make_float4(a0 + bccS[0], a1 + bccS[1], a2 + bccS[2], a3 + bccS[3]);
            op[1] = make_float4(a4 + bccS[4], a5 + bccS[5], a6 + bccS[6], a7 + bccS[7]);
            op[2] = make_float4(a8 + bccS[8], a9 + bccS[9], a10 + bccS[10], a11 + bccS[11]);
        }
    }
}

// ---- launch ---------------------------------------------------------------

extern "C" void kernel_launch(void* const* d_in, const int* in_sizes, int n_in,
                              void* d_out, int out_size, void* d_ws, size_t ws_size,
                              hipStream_t stream) {
    const float* x    = (const float*)d_in[0];
    const int*   edge = (const int*)d_in[1];
    const int*   src  = edge;
    const int*   dst  = edge + EE;
    const float* W1  = (const float*)d_in[2];  const float* b1  = (const float*)d_in[3];
    const float* W2  = (const float*)d_in[4];  const float* b2  = (const float*)d_in[5];
    const float* W3  = (const float*)d_in[6];  const float* b3  = (const float*)d_in[7];
    const float* Wc1 = (const float*)d_in[8];  const float* bc1 = (const float*)d_in[9];
    const float* Wc2 = (const float*)d_in[10]; const float* bc2 = (const float*)d_in[11];
    float* outp = (float*)d_out;

    char* p = (char*)d_ws;
    int*   cnt     = (int*)p;   p += 200064;          // NN ints, padded
    int*   row_ptr = (int*)p;   p += 200064;          // NN+1 ints, padded
    float* dinv    = (float*)p; p += 200064;
    int*   sums    = (int*)p;   p += 256;
    int*   offs    = (int*)p;   p += 256;
    int2*  e_sn    = (int2*)p;  p += (size_t)EE * 8;  // packed {src, dinv[src]}
    float* xp      = (float*)p; p += (size_t)NN * 32 * 4;    // padded pre-folded x
    short* q       = (short*)p; p += (size_t)NN * HID * 2;   // int16 tanh (q1/q2 alias)
    float* aggf    = (float*)p; p += (size_t)NN * HID * 4;   // fp32 agg (gemm input)
    float* Wcc     = (float*)p; p += HID * NCLS * 4;         // collapsed head weight
    float* bcc     = (float*)p; p += 256;                    // collapsed head bias

    // graph build (+ collapsed head weights — independent, cheap)
    hipMemsetAsync(cnt, 0, (size_t)NN * 4, stream);
    k_wcc       <<<(HID * NCLS + 255) / 256, 256, 0, stream>>>(Wc1, bc1, Wc2, bc2, Wcc, bcc);
    k_count     <<<(EE + 255) / 256, 256, 0, stream>>>(dst, cnt, EE);
    k_scan_local<<<NB, 256, 0, stream>>>(cnt, row_ptr, dinv, sums);
    k_scan_sums <<<1, 64, 0, stream>>>(sums, offs, row_ptr);
    k_scan_apply<<<NB, 256, 0, stream>>>(row_ptr, offs, cnt);   // cnt becomes cursor
    k_fill      <<<(EE + 255) / 256, 256, 0, stream>>>(src, dst, cnt, dinv, e_sn, EE);
    k_pad       <<<(NN * 32) / 256, 256, 0, stream>>>(x, dinv, xp);

    // layer 1: q1 = quant(tanh((A@x)@W1 + b1))
    k_l1  <<<NN / 4, 256, 0, stream>>>(xp, W1, b1, row_ptr, e_sn, dinv, q);
    // layer 2: agg(q1) -> gemm+tanh -> q2   (q2 aliases q1; stream-ordered)
    k_aggq <<<NN / 4, 256, 0, stream>>>(q, row_ptr, e_sn, dinv, aggf);
    k_gemmT<<<(NN + 63) / 64, 256, 0, stream>>>(aggf, W2, b2, q, nullptr, nullptr, nullptr);
    // layer 3: agg(q2) -> gemm+tanh -> fused head (h3 never hits global)
    k_aggq <<<NN / 4, 256, 0, stream>>>(q, row_ptr, e_sn, dinv, aggf);
    k_gemmT<<<(NN + 63) / 64, 256, 0, stream>>>(aggf, W3, b3, nullptr, Wcc, bcc, outp);
}

// Round 2
// 304.498 us; speedup vs baseline: 1.1220x; 1.0869x over previous
//
#include <hip/hip_runtime.h>
#include <math.h>

#define NN 50000
#define EE 640000
#define IND 23
#define HID 128
#define MIDD 64
#define NCLS 12
#define NB 49          // ceil(NN / 1024) scan chunks
#define QS 32766.0f
#define INVQS (1.0f / 32766.0f)

typedef short short8v __attribute__((ext_vector_type(8)));
typedef float f32x4 __attribute__((ext_vector_type(4)));

// bf16 helpers (RNE), bit-exact and header-free
__device__ __forceinline__ short f2bf(float f) {
    unsigned u = __float_as_uint(f);
    unsigned r = (u + 0x7FFFu + ((u >> 16) & 1u)) >> 16;
    return (short)r;
}
__device__ __forceinline__ float bf2f(short s) {
    return __uint_as_float(((unsigned)(unsigned short)s) << 16);
}

// ---- graph build ----------------------------------------------------------

__global__ void k_count(const int* __restrict__ dst, int* __restrict__ cnt, int e) {
    int i = blockIdx.x * blockDim.x + threadIdx.x;
    if (i < e) atomicAdd(&cnt[dst[i]], 1);
}

__global__ __launch_bounds__(256) void k_scan_local(const int* __restrict__ cnt,
                                                    int* __restrict__ row_ptr,
                                                    float* __restrict__ dinv,
                                                    int* __restrict__ sums) {
    __shared__ int wtot[4];
    const int tid = threadIdx.x;
    const int wid = tid >> 6, lane = tid & 63;
    const int base = blockIdx.x * 1024 + tid * 4;
    int v[4];
#pragma unroll
    for (int t = 0; t < 4; ++t) {
        int i = base + t;
        v[t] = (i < NN) ? cnt[i] : 0;
        if (i < NN) dinv[i] = rsqrtf((float)v[t] + 1.0f);  // +1 self loop
    }
    int slocal = v[0] + v[1] + v[2] + v[3];
    int val = slocal;
#pragma unroll
    for (int off = 1; off < 64; off <<= 1) {
        int t = __shfl_up(val, off, 64);
        if (lane >= off) val += t;
    }
    if (lane == 63) wtot[wid] = val;
    __syncthreads();
    int woff = 0;
#pragma unroll
    for (int w = 0; w < 4; ++w) woff += (w < wid) ? wtot[w] : 0;
    int run = woff + val - slocal;
#pragma unroll
    for (int t = 0; t < 4; ++t) {
        int i = base + t;
        if (i < NN) row_ptr[i] = run;
        run += v[t];
    }
    if (tid == 255) sums[blockIdx.x] = woff + val;
}

__global__ void k_scan_sums(const int* __restrict__ sums, int* __restrict__ offs,
                            int* __restrict__ row_ptr) {
    const int lane = threadIdx.x;
    int v = (lane < NB) ? sums[lane] : 0;
    int val = v;
#pragma unroll
    for (int off = 1; off < 64; off <<= 1) {
        int t = __shfl_up(val, off, 64);
        if (lane >= off) val += t;
    }
    if (lane < NB) offs[lane] = val - v;
    if (lane == NB - 1) row_ptr[NN] = val;
}

// lean 49-block scan finalize ONLY (pad lives in its own wide launch —
// merging it here collapsed to 2% occupancy and cost ~50 µs, round 11)
__global__ __launch_bounds__(256) void k_scan_apply(int* __restrict__ row_ptr,
                                                    const int* __restrict__ offs,
                                                    int* __restrict__ cursor) {
    const int base = blockIdx.x * 1024 + threadIdx.x * 4;
    const int o = offs[blockIdx.x];
#pragma unroll
    for (int t = 0; t < 4; ++t) {
        int i = base + t;
        if (i < NN) {
            int rp = row_ptr[i] + o;
            row_ptr[i] = rp;
            cursor[i] = rp;
        }
    }
}

// fill CSR with packed {src, dinv[src]} — one gather pass instead of two
__global__ void k_fill(const int* __restrict__ src, const int* __restrict__ dst,
                       int* __restrict__ cursor, const float* __restrict__ dinv,
                       int2* __restrict__ e_sn, int e) {
    int i = blockIdx.x * blockDim.x + threadIdx.x;
    if (i < e) {
        int s = src[i];
        int d = dst[i];
        float w = dinv[s];
        int pos = atomicAdd(&cursor[d], 1);
        e_sn[pos] = make_int2(s, __float_as_int(w));
    }
}

// pad x rows 23 -> 32 floats, pre-scaled by dinv[node] (wide 6250-block grid)
__global__ __launch_bounds__(256) void k_pad(const float* __restrict__ x,
                                             const float* __restrict__ dinv,
                                             float* __restrict__ xp) {
    int i = blockIdx.x * 256 + threadIdx.x;   // over NN*32
    int node = i >> 5, f = i & 31;
    xp[i] = (f < IND) ? x[node * IND + f] * dinv[node] : 0.f;
}

// collapse the linear head: Wcc = Wc1 @ Wc2 (128x12), bcc = bc1 @ Wc2 + bc2.
// Valid: no nonlinearity between the two head matmuls (dropout = identity).
__global__ void k_wcc(const float* __restrict__ Wc1, const float* __restrict__ bc1,
                      const float* __restrict__ Wc2, const float* __restrict__ bc2,
                      float* __restrict__ Wcc, float* __restrict__ bcc) {
    int t = blockIdx.x * 256 + threadIdx.x;
    if (t < HID * NCLS) {
        int k = t / NCLS, c = t % NCLS;
        float s = 0.f;
#pragma unroll 8
        for (int j = 0; j < MIDD; ++j) s += Wc1[k * MIDD + j] * Wc2[j * NCLS + c];
        Wcc[t] = s;
    }
    if (t < NCLS) {
        float s = bc2[t];
#pragma unroll 8
        for (int j = 0; j < MIDD; ++j) s += bc1[j] * Wc2[j * NCLS + t];
        bcc[t] = s;
    }
}

// split W (128x128 fp32, k-major) into hi/lo bf16 MFMA B-fragment tables.
// Storage: short idx = ((t*4+g)*128 + col)*8 + j  <=>  W[t*32+g*8+j][col],
// so lane l of a wave reads its 16B frag at short8v idx (t*4+(l>>4))*128+col.
__global__ void k_wsplit(const float* __restrict__ Wa, const float* __restrict__ Wb,
                         short* __restrict__ hiA, short* __restrict__ loA,
                         short* __restrict__ hiB, short* __restrict__ loB) {
    int i = blockIdx.x * 256 + threadIdx.x;   // 16384 = 128*128
    const float* W = (blockIdx.y == 0) ? Wa : Wb;
    short* hi = (blockIdx.y == 0) ? hiA : hiB;
    short* lo = (blockIdx.y == 0) ? loA : loB;
    int k = i >> 7, c = i & 127;
    float w = W[i];
    short h = f2bf(w);
    short l = f2bf(w - bf2f(h));
    int t = k >> 5, g = (k >> 3) & 3, j = k & 7;
    int idx = ((t * 4 + g) * 128 + c) * 8 + j;
    hi[idx] = h;
    lo[idx] = l;
}

// ---- layer 1 fused: q1 = quant( tanh( (A @ x) @ W1 + b1 ) ) ---------------
__global__ __launch_bounds__(256) void k_l1(const float* __restrict__ xp,
                                            const float* __restrict__ W1,
                                            const float* __restrict__ b1,
                                            const int* __restrict__ row_ptr,
                                            const int2* __restrict__ e_sn,
                                            const float* __restrict__ dinv,
                                            short* __restrict__ outq) {
    const int tid = threadIdx.x;
    const int i = blockIdx.x * 4 + (tid >> 6);
    const int lane = tid & 63;
    const int slot = lane >> 3;     // 8 edge slots
    const int f = lane & 7;         // float4 index within 32-float row
    const float4* xp4 = (const float4*)xp;
    const int beg = row_ptr[i];
    const int deg = row_ptr[i + 1] - beg;
    float4 acc = make_float4(0.f, 0.f, 0.f, 0.f);
    for (int base = 0; base < deg; base += 64) {
        const int cnt = min(64, deg - base);
        int s_l = 0;
        if (lane < cnt) s_l = e_sn[beg + base + lane].x;
        int e = 0;
        for (; e + 8 <= cnt; e += 8) {
            int s = __shfl(s_l, e + slot, 64);
            float4 v = xp4[s * 8 + f];
            acc.x += v.x; acc.y += v.y; acc.z += v.z; acc.w += v.w;
        }
        if (e < cnt) {                          // wave-uniform shfl
            int s = __shfl(s_l, e + slot, 64);
            if (e + slot < cnt) {
                float4 v = xp4[s * 8 + f];
                acc.x += v.x; acc.y += v.y; acc.z += v.z; acc.w += v.w;
            }
        }
    }
#pragma unroll
    for (int off = 32; off >= 8; off >>= 1) {
        acc.x += __shfl_down(acc.x, off, 64);
        acc.y += __shfl_down(acc.y, off, 64);
        acc.z += __shfl_down(acc.z, off, 64);
        acc.w += __shfl_down(acc.w, off, 64);
    }
    const float di = dinv[i];
    if (lane < 8) {
        float4 v = xp4[i * 8 + lane];   // self row (pre-folded)
        acc.x = (acc.x + v.x) * di; acc.y = (acc.y + v.y) * di;
        acc.z = (acc.z + v.z) * di; acc.w = (acc.w + v.w) * di;
    }
    float a0 = b1[lane], a1 = b1[lane + 64];
#pragma unroll
    for (int k = 0; k < IND; ++k) {
        float comp = ((k & 3) == 0) ? acc.x : ((k & 3) == 1) ? acc.y
                   : ((k & 3) == 2) ? acc.z : acc.w;
        float xk = __shfl(comp, k >> 2, 64);
        a0 += xk * W1[k * HID + lane];
        a1 += xk * W1[k * HID + lane + 64];
    }
    outq[i * HID + lane]      = (short)__float2int_rn(tanhf(a0) * QS);
    outq[i * HID + lane + 64] = (short)__float2int_rn(tanhf(a1) * QS);
}

// ---- aggregation over int16 tanh rows (lean: low VGPR, 0 LDS, high occ) ---
__global__ __launch_bounds__(256) void k_aggq(const short* __restrict__ hq,
                                              const int* __restrict__ row_ptr,
                                              const int2* __restrict__ e_sn,
                                              const float* __restrict__ dinv,
                                              float* __restrict__ aggf) {
    const int tid = threadIdx.x;
    const int i = blockIdx.x * 4 + (tid >> 6);
    const int lane = tid & 63;
    const int slot = lane >> 4;     // 4 edge slots
    const int f = lane & 15;        // short8 index within 128-short row
    const short8v* h8 = (const short8v*)hq;
    const int beg = row_ptr[i];
    const int deg = row_ptr[i + 1] - beg;
    float facc[8];
#pragma unroll
    for (int t = 0; t < 8; ++t) facc[t] = 0.f;
    for (int base = 0; base < deg; base += 64) {
        const int cnt = min(64, deg - base);
        int s_l = 0; float n_l = 0.f;
        if (lane < cnt) {
            int2 sn = e_sn[beg + base + lane];
            s_l = sn.x;
            n_l = __int_as_float(sn.y);
        }
        int e = 0;
#pragma unroll 4
        for (; e + 4 <= cnt; e += 4) {
            int s = __shfl(s_l, e + slot, 64);
            float nr = __shfl(n_l, e + slot, 64);
            short8v v = h8[s * 16 + f];
#pragma unroll
            for (int t = 0; t < 8; ++t) facc[t] += (float)v[t] * nr;
        }
        if (e < cnt) {                          // wave-uniform shfl
            int s = __shfl(s_l, e + slot, 64);
            float nr = __shfl(n_l, e + slot, 64);
            if (e + slot < cnt) {
                short8v v = h8[s * 16 + f];
#pragma unroll
                for (int t = 0; t < 8; ++t) facc[t] += (float)v[t] * nr;
            }
        }
    }
#pragma unroll
    for (int off = 32; off >= 16; off >>= 1)
#pragma unroll
        for (int t = 0; t < 8; ++t) facc[t] += __shfl_down(facc[t], off, 64);
    if (lane < 16) {
        const float di = dinv[i];
        const float sc = di * INVQS;
        short8v v = h8[i * 16 + lane];          // self row
        float4 o0, o1;
        o0.x = (facc[0] + di * (float)v[0]) * sc;
        o0.y = (facc[1] + di * (float)v[1]) * sc;
        o0.z = (facc[2] + di * (float)v[2]) * sc;
        o0.w = (facc[3] + di * (float)v[3]) * sc;
        o1.x = (facc[4] + di * (float)v[4]) * sc;
        o1.y = (facc[5] + di * (float)v[5]) * sc;
        o1.z = (facc[6] + di * (float)v[6]) * sc;
        o1.w = (facc[7] + di * (float)v[7]) * sc;
        ((float4*)aggf)[i * 32 + lane * 2]     = o0;
        ((float4*)aggf)[i * 32 + lane * 2 + 1] = o1;
    }
}

// ---- MFMA split-bf16 GEMM: C = A @ W via Ahi@Whi + Ahi@Wlo + Alo@Whi ------
// Wave = 16 rows x 128 cols; block = 64 rows. 96 mfma_f32_16x16x32_bf16/wave.
// Fragment layouts (verified guide mappings):
//   A: lane l holds A[l&15][8*(l>>4)+j]   B: lane l holds B[8*(l>>4)+j][l&15]
//   D: lane l holds D[4*(l>>4)+r][l&15]
__device__ __forceinline__ void gemm_core(const float* __restrict__ hin,
                                          const short8v* __restrict__ whi8,
                                          const short8v* __restrict__ wlo8,
                                          int row, bool rv, int g, int c16,
                                          f32x4 acc[8]) {
#pragma unroll
    for (int t = 0; t < 4; ++t) {
        float4 a0 = make_float4(0.f, 0.f, 0.f, 0.f), a1 = a0;
        if (rv) {
            const float4* hp = (const float4*)&hin[row * HID + t * 32 + g * 8];
            a0 = hp[0]; a1 = hp[1];
        }
        float av[8];
        av[0] = a0.x; av[1] = a0.y; av[2] = a0.z; av[3] = a0.w;
        av[4] = a1.x; av[5] = a1.y; av[6] = a1.z; av[7] = a1.w;
        short8v ahi, alo;
#pragma unroll
        for (int j = 0; j < 8; ++j) {
            short h = f2bf(av[j]);
            ahi[j] = h;
            alo[j] = f2bf(av[j] - bf2f(h));
        }
        const int wb = (t * 4 + g) * 128 + c16;
#pragma unroll
        for (int n = 0; n < 8; ++n) {
            short8v bh = whi8[wb + n * 16];
            short8v bl = wlo8[wb + n * 16];
            acc[n] = __builtin_amdgcn_mfma_f32_16x16x32_bf16(ahi, bh, acc[n], 0, 0, 0);
            acc[n] = __builtin_amdgcn_mfma_f32_16x16x32_bf16(ahi, bl, acc[n], 0, 0, 0);
            acc[n] = __builtin_amdgcn_mfma_f32_16x16x32_bf16(alo, bh, acc[n], 0, 0, 0);
        }
    }
}

// layer 2: qout = int16 quant(tanh(A@W + b))
__global__ __launch_bounds__(256) void k_gemm_q(const float* __restrict__ hin,
                                                const short* __restrict__ whi,
                                                const short* __restrict__ wlo,
                                                const float* __restrict__ bias,
                                                short* __restrict__ qout) {
    const int tid = threadIdx.x;
    const int lane = tid & 63, w = tid >> 6;
    const int g = lane >> 4, c16 = lane & 15;
    const int rbase = blockIdx.x * 64 + w * 16;
    f32x4 acc[8];
#pragma unroll
    for (int n = 0; n < 8; ++n) acc[n] = f32x4{0.f, 0.f, 0.f, 0.f};
    gemm_core(hin, (const short8v*)whi, (const short8v*)wlo,
              rbase + c16, (rbase + c16) < NN, g, c16, acc);
#pragma unroll
    for (int n = 0; n < 8; ++n) {
        const float bb = bias[n * 16 + c16];
#pragma unroll
        for (int r = 0; r < 4; ++r) {
            int nd = rbase + 4 * g + r;
            if (nd < NN) {
                float v = tanhf(acc[n][r] + bb);
                qout[nd * HID + n * 16 + c16] = (short)__float2int_rn(v * QS);
            }
        }
    }
}

// layer 3 + fused head: out = tanh(A@W + b) @ Wcc + bcc  (h3 never hits HBM;
// head works directly on the MFMA D-register layout, 16-lane shfl reduce)
__global__ __launch_bounds__(256) void k_gemm_head(const float* __restrict__ hin,
                                                   const short* __restrict__ whi,
                                                   const short* __restrict__ wlo,
                                                   const float* __restrict__ bias,
                                                   const float* __restrict__ Wcc,
                                                   const float* __restrict__ bcc,
                                                   float* __restrict__ outp) {
    __shared__ float WccS[HID * NCLS + 16];
    const int tid = threadIdx.x;
    const int lane = tid & 63, w = tid >> 6;
    const int g = lane >> 4, c16 = lane & 15;
    const int rbase = blockIdx.x * 64 + w * 16;
    for (int t = tid; t < HID * NCLS; t += 256) WccS[t] = Wcc[t];
    if (tid < NCLS) WccS[HID * NCLS + tid] = bcc[tid];
    __syncthreads();
    f32x4 acc[8];
#pragma unroll
    for (int n = 0; n < 8; ++n) acc[n] = f32x4{0.f, 0.f, 0.f, 0.f};
    gemm_core(hin, (const short8v*)whi, (const short8v*)wlo,
              rbase + c16, (rbase + c16) < NN, g, c16, acc);
    float part[4][12];
#pragma unroll
    for (int r = 0; r < 4; ++r)
#pragma unroll
        for (int c = 0; c < 12; ++c) part[r][c] = 0.f;
#pragma unroll
    for (int n = 0; n < 8; ++n) {
        const float bb = bias[n * 16 + c16];
        const float4* wr = (const float4*)&WccS[(n * 16 + c16) * NCLS];
        float4 wa = wr[0], wb = wr[1], wc = wr[2];
#pragma unroll
        for (int r = 0; r < 4; ++r) {
            float v = tanhf(acc[n][r] + bb);
            part[r][0]  += v * wa.x; part[r][1]  += v * wa.y;
            part[r][2]  += v * wa.z; part[r][3]  += v * wa.w;
            part[r][4]  += v * wb.x; part[r][5]  += v * wb.y;
            part[r][6]  += v * wb.z; part[r][7]  += v * wb.w;
            part[r][8]  += v * wc.x; part[r][9]  += v * wc.y;
            part[r][10] += v * wc.z; part[r][11] += v * wc.w;
        }
    }
#pragma unroll
    for (int off = 8; off; off >>= 1)
#pragma unroll
        for (int r = 0; r < 4; ++r)
#pragma unroll
            for (int c = 0; c < 12; ++c)
                part[r][c] += __shfl_down(part[r][c], off, 64);
    if (c16 == 0) {
#pragma unroll
        for (int r = 0; r < 4; ++r) {
            int nd = rbase + 4 * g + r;
            if (nd < NN) {
                float4* op = (float4*)&outp[nd * NCLS];
                op[0] = make_float4(part[r][0] + WccS[HID * NCLS + 0],
                                    part[r][1] + WccS[HID * NCLS + 1],
                                    part[r][2] + WccS[HID * NCLS + 2],
                                    part[r][3] + WccS[HID * NCLS + 3]);
                op[1] = make_float4(part[r][4] + WccS[HID * NCLS + 4],
                                    part[r][5] + WccS[HID * NCLS + 5],
                                    part[r][6] + WccS[HID * NCLS + 6],
                                    part[r][7] + WccS[HID * NCLS + 7]);
                op[2] = make_float4(part[r][8] + WccS[HID * NCLS + 8],
                                    part[r][9] + WccS[HID * NCLS + 9],
                                    part[r][10] + WccS[HID * NCLS + 10],
                                    part[r][11] + WccS[HID * NCLS + 11]);
            }
        }
    }
}

// ---- launch ---------------------------------------------------------------

extern "C" void kernel_launch(void* const* d_in, const int* in_sizes, int n_in,
                              void* d_out, int out_size, void* d_ws, size_t ws_size,
                              hipStream_t stream) {
    const float* x    = (const float*)d_in[0];
    const int*   edge = (const int*)d_in[1];
    const int*   src  = edge;
    const int*   dst  = edge + EE;
    const float* W1  = (const float*)d_in[2];  const float* b1  = (const float*)d_in[3];
    const float* W2  = (const float*)d_in[4];  const float* b2  = (const float*)d_in[5];
    const float* W3  = (const float*)d_in[6];  const float* b3  = (const float*)d_in[7];
    const float* Wc1 = (const float*)d_in[8];  const float* bc1 = (const float*)d_in[9];
    const float* Wc2 = (const float*)d_in[10]; const float* bc2 = (const float*)d_in[11];
    float* outp = (float*)d_out;

    char* p = (char*)d_ws;
    int*   cnt     = (int*)p;   p += 200064;          // NN ints, padded
    int*   row_ptr = (int*)p;   p += 200064;          // NN+1 ints, padded
    float* dinv    = (float*)p; p += 200064;
    int*   sums    = (int*)p;   p += 256;
    int*   offs    = (int*)p;   p += 256;
    int2*  e_sn    = (int2*)p;  p += (size_t)EE * 8;  // packed {src, dinv[src]}
    float* xp      = (float*)p; p += (size_t)NN * 32 * 4;    // padded pre-folded x
    short* q       = (short*)p; p += (size_t)NN * HID * 2;   // int16 tanh (q1/q2 alias)
    float* aggf    = (float*)p; p += (size_t)NN * HID * 4;   // fp32 agg (gemm input)
    float* Wcc     = (float*)p; p += HID * NCLS * 4;         // collapsed head weight
    float* bcc     = (float*)p; p += 256;                    // collapsed head bias
    short* w2hi    = (short*)p; p += 32768;           // bf16 frag tables (128x128)
    short* w2lo    = (short*)p; p += 32768;
    short* w3hi    = (short*)p; p += 32768;
    short* w3lo    = (short*)p; p += 32768;

    // graph build (+ weight preprocessing — independent, cheap)
    hipMemsetAsync(cnt, 0, (size_t)NN * 4, stream);
    k_wcc       <<<(HID * NCLS + 255) / 256, 256, 0, stream>>>(Wc1, bc1, Wc2, bc2, Wcc, bcc);
    k_wsplit    <<<dim3(64, 2), 256, 0, stream>>>(W2, W3, w2hi, w2lo, w3hi, w3lo);
    k_count     <<<(EE + 255) / 256, 256, 0, stream>>>(dst, cnt, EE);
    k_scan_local<<<NB, 256, 0, stream>>>(cnt, row_ptr, dinv, sums);
    k_scan_sums <<<1, 64, 0, stream>>>(sums, offs, row_ptr);
    k_scan_apply<<<NB, 256, 0, stream>>>(row_ptr, offs, cnt);   // cnt becomes cursor
    k_fill      <<<(EE + 255) / 256, 256, 0, stream>>>(src, dst, cnt, dinv, e_sn, EE);
    k_pad       <<<(NN * 32) / 256, 256, 0, stream>>>(x, dinv, xp);

    // layer 1: q1 = quant(tanh((A@x)@W1 + b1))
    k_l1  <<<NN / 4, 256, 0, stream>>>(xp, W1, b1, row_ptr, e_sn, dinv, q);
    // layer 2: agg(q1) -> mfma gemm+tanh -> q2   (q2 aliases q1; stream-ordered)
    k_aggq     <<<NN / 4, 256, 0, stream>>>(q, row_ptr, e_sn, dinv, aggf);
    k_gemm_q   <<<(NN + 63) / 64, 256, 0, stream>>>(aggf, w2hi, w2lo, b2, q);
    // layer 3: agg(q2) -> mfma gemm+tanh -> fused head (h3 never hits global)
    k_aggq     <<<NN / 4, 256, 0, stream>>>(q, row_ptr, e_sn, dinv, aggf);
    k_gemm_head<<<(NN + 63) / 64, 256, 0, stream>>>(aggf, w3hi, w3lo, b3, Wcc, bcc, outp);
}